// Round 1
// baseline (585.169 us; speedup 1.0000x reference)
//
#include <hip/hip_runtime.h>
#include <math.h>

#define B 2
#define L 512
#define DIN 400
#define D 256
#define H 8
#define DKK 32
#define DFF 1024
#define NL 2
#define NCLS 2

// ---------------------------------------------------------------------------
// prep: pwm[k][h] = mean_d pos_w[k, h*32+d]; pbm[h] = mean_d pos_b[h*32+d];
//       T[c*128 + (p+64)][h] = sum_r sin(p/dm[r])*pwm[c*128+r][h]
//                                    + cos(p/dm[r])*pwm[c*128+64+r][h]
// ---------------------------------------------------------------------------
__global__ void prep_kernel(const float* __restrict__ pos_w,
                            const float* __restrict__ pos_b,
                            float* __restrict__ T, float* __restrict__ pbm) {
  __shared__ float s_pwm[256 * 8];
  __shared__ float s_inv[64];
  int t = threadIdx.x;  // 256 threads
  {
    int k = t;
    for (int h = 0; h < 8; ++h) {
      float s = 0.f;
      for (int d = 0; d < DKK; ++d) s += pos_w[k * D + h * DKK + d];
      s_pwm[k * 8 + h] = s * (1.0f / DKK);
    }
  }
  if (t < 64) s_inv[t] = powf(10000.0f, -(float)t * (1.0f / 64.0f));
  if (t < 8) {
    float s = 0.f;
    for (int d = 0; d < DKK; ++d) s += pos_b[t * DKK + d];
    pbm[t] = s * (1.0f / DKK);
  }
  __syncthreads();
  // t encodes c*128 + (p+64)
  int c = t >> 7;
  float p = (float)((t & 127) - 64);
  float acc[8] = {0, 0, 0, 0, 0, 0, 0, 0};
  for (int r = 0; r < 64; ++r) {
    float a = p * s_inv[r];
    float sv = sinf(a), cv = cosf(a);
    const float* ps = &s_pwm[(c * 128 + r) * 8];
    const float* pc = &s_pwm[(c * 128 + 64 + r) * 8];
#pragma unroll
    for (int h = 0; h < 8; ++h) acc[h] += sv * ps[h] + cv * pc[h];
  }
  for (int h = 0; h < 8; ++h) T[t * 8 + h] = acc[h];
}

// ---------------------------------------------------------------------------
// generic row-blocked matmul: C[M,N] = act(A[M,K] @ W[K,N] + bias)
// RB rows per block, 256 threads = 256 cols per block-column, grid (M/RB, N/256)
// act: 0 none, 1 relu, 2 selu
// ---------------------------------------------------------------------------
template <int RB>
__global__ void matmul_kernel(const float* __restrict__ A,
                              const float* __restrict__ W,
                              const float* __restrict__ bias,
                              float* __restrict__ C, int K, int N, int act) {
  extern __shared__ float arows[];  // RB * K
  int row0 = blockIdx.x * RB;
  int t = threadIdx.x;
  for (int e = t; e < RB * K; e += 256) {
    int r = e / K, kk = e - r * K;
    arows[e] = A[(row0 + r) * K + kk];
  }
  __syncthreads();
  int c = blockIdx.y * 256 + t;
  float bb = bias ? bias[c] : 0.0f;
  float acc[RB];
#pragma unroll
  for (int r = 0; r < RB; ++r) acc[r] = bb;
  for (int kk = 0; kk < K; ++kk) {
    float wv = W[kk * N + c];
#pragma unroll
    for (int r = 0; r < RB; ++r) acc[r] += arows[r * K + kk] * wv;
  }
  const float s_alpha = 1.6732632423543772f, s_scale = 1.0507009873554805f;
#pragma unroll
  for (int r = 0; r < RB; ++r) {
    float v = acc[r];
    if (act == 1) v = fmaxf(v, 0.0f);
    else if (act == 2) v = s_scale * (v > 0.f ? v : s_alpha * expm1f(v));
    C[(row0 + r) * N + c] = v;
  }
}

// ---------------------------------------------------------------------------
// scores + mask + pos-bias + softmax -> attn (B,H,L,L)
// block per (b,h,i), 256 threads, each thread handles j = t and t+256
// ---------------------------------------------------------------------------
__global__ void scores_softmax_kernel(const float* __restrict__ q,
                                      const float* __restrict__ k,
                                      const float* __restrict__ pos_ind,
                                      const float* __restrict__ fmask,
                                      const float* __restrict__ T,
                                      const float* __restrict__ pbm,
                                      float* __restrict__ attn) {
  __shared__ float sT[2048];
  __shared__ float qrow[DKK];
  __shared__ float red[256];
  __shared__ float s_pbm[8];
  int t = threadIdx.x;
  for (int e = t; e < 2048; e += 256) sT[e] = T[e];
  int i = blockIdx.x % L;
  int bh = blockIdx.x / L;
  int h = bh & 7, b = bh >> 3;
  if (t < DKK) qrow[t] = q[(b * L + i) * D + h * DKK + t];
  if (t < 8) s_pbm[t] = pbm[t];
  float fmi = fmask[b * L + i];
  __syncthreads();
  const float scale = 0.17677669529663687f;  // 1/sqrt(32)
  float s[2];
#pragma unroll
  for (int u = 0; u < 2; ++u) {
    int j = t + u * 256;
    float fmj = fmask[b * L + j];
    bool aj = (1.0f - fmj) > 0.0f;
    bool ai = (1.0f - fmi) > 0.0f;
    int di = i - j;
    bool local_np = (di >= 9) || (di <= -8);        // outside local window
    int ad = di < 0 ? -di : di;
    bool dil_np = (ad & 15) != 0;                   // not on dilation stride
    bool m = (dil_np || aj || ai) && (local_np || aj);
    if (m) {
      s[u] = -1e9f;
    } else {
      const float* kr = &k[(b * L + j) * D + h * DKK];
      float dot = 0.f;
#pragma unroll
      for (int d = 0; d < DKK; ++d) dot += qrow[d] * kr[d];
      int pidx = ((b * L + i) * L + j) * 2;
      int p0 = (int)floorf(pos_ind[pidx]);
      int p1 = (int)floorf(pos_ind[pidx + 1]);
      p0 = min(max(p0, -64), 63);
      p1 = min(max(p1, -64), 63);
      float pb = sT[(p0 + 64) * 8 + h] + sT[(128 + p1 + 64) * 8 + h] + s_pbm[h];
      s[u] = dot * scale + pb;
    }
  }
  // block max
  float mx = fmaxf(s[0], s[1]);
  red[t] = mx;
  __syncthreads();
  for (int w = 128; w > 0; w >>= 1) {
    if (t < w) red[t] = fmaxf(red[t], red[t + w]);
    __syncthreads();
  }
  mx = red[0];
  __syncthreads();
  float e0 = expf(s[0] - mx), e1 = expf(s[1] - mx);
  red[t] = e0 + e1;
  __syncthreads();
  for (int w = 128; w > 0; w >>= 1) {
    if (t < w) red[t] += red[t + w];
    __syncthreads();
  }
  float inv = 1.0f / red[0];
  int base = (bh * L + i) * L;
  attn[base + t] = e0 * inv;
  attn[base + t + 256] = e1 * inv;
}

// ---------------------------------------------------------------------------
// o[b,i,h,d] = sum_m attn[b,h,i,m] * v[b,m,h,d]; block per (b,i), 256 thr
// ---------------------------------------------------------------------------
__global__ void attn_v_kernel(const float* __restrict__ attn,
                              const float* __restrict__ v,
                              float* __restrict__ o) {
  __shared__ float arow[H * L];  // 16 KB
  int row = blockIdx.x;  // b*L + i
  int b = row / L, i = row - b * L;
  int t = threadIdx.x;
  for (int idx = t; idx < H * L; idx += 256) {
    int hh = idx >> 9, m = idx & 511;
    arow[idx] = attn[((b * H + hh) * L + i) * L + m];
  }
  __syncthreads();
  int h = t >> 5, d = t & 31;
  const float* ah = &arow[h * L];
  float acc = 0.f;
  for (int m = 0; m < L; ++m) acc += ah[m] * v[(b * L + m) * D + h * DKK + d];
  o[row * D + t] = acc;
}

// ---------------------------------------------------------------------------
// x = LayerNorm(resid + y) * g + b   (block per row, 256 threads = D)
// ---------------------------------------------------------------------------
__global__ void ln_residual_kernel(const float* __restrict__ resid,
                                   const float* __restrict__ y,
                                   const float* __restrict__ g,
                                   const float* __restrict__ bta,
                                   float* __restrict__ outx) {
  __shared__ float red[256];
  int row = blockIdx.x;
  int t = threadIdx.x;
  float val = resid[row * D + t] + y[row * D + t];
  red[t] = val;
  __syncthreads();
  for (int w = 128; w > 0; w >>= 1) {
    if (t < w) red[t] += red[t + w];
    __syncthreads();
  }
  float mean = red[0] * (1.0f / D);
  __syncthreads();
  float diff = val - mean;
  red[t] = diff * diff;
  __syncthreads();
  for (int w = 128; w > 0; w >>= 1) {
    if (t < w) red[t] += red[t + w];
    __syncthreads();
  }
  float var = red[0] * (1.0f / D);
  float rs = rsqrtf(var + 1e-5f);
  outx[row * D + t] = diff * rs * g[t] + bta[t];
}

// ---------------------------------------------------------------------------
// final classifier + 2-way softmax; thread per row
// ---------------------------------------------------------------------------
__global__ void cls_kernel(const float* __restrict__ x,
                           const float* __restrict__ cw,
                           const float* __restrict__ cb,
                           float* __restrict__ out) {
  int row = blockIdx.x * 256 + threadIdx.x;
  if (row >= B * L) return;
  float l0 = cb[0], l1 = cb[1];
  for (int kk = 0; kk < D; ++kk) {
    float xv = x[row * D + kk];
    l0 += xv * cw[kk * NCLS + 0];
    l1 += xv * cw[kk * NCLS + 1];
  }
  float mx = fmaxf(l0, l1);
  float e0 = expf(l0 - mx), e1 = expf(l1 - mx);
  float inv = 1.0f / (e0 + e1);
  out[row * 2 + 0] = e0 * inv;
  out[row * 2 + 1] = e1 * inv;
}

extern "C" void kernel_launch(void* const* d_in, const int* in_sizes, int n_in,
                              void* d_out, int out_size, void* d_ws,
                              size_t ws_size, hipStream_t stream) {
  const float* feature  = (const float*)d_in[0];
  const float* pos_ind  = (const float*)d_in[1];
  const float* fmaskp   = (const float*)d_in[2];
  const float* w_reduce = (const float*)d_in[3];
  const float* b_reduce = (const float*)d_in[4];
  const float* pos_w    = (const float*)d_in[5];
  const float* pos_b    = (const float*)d_in[6];
  const float* wq       = (const float*)d_in[7];
  const float* wk       = (const float*)d_in[8];
  const float* wv       = (const float*)d_in[9];
  const float* wo       = (const float*)d_in[10];
  const float* ln1_g    = (const float*)d_in[11];
  const float* ln1_b    = (const float*)d_in[12];
  const float* w1       = (const float*)d_in[13];
  const float* b1       = (const float*)d_in[14];
  const float* w2       = (const float*)d_in[15];
  const float* b2       = (const float*)d_in[16];
  const float* ln2_g    = (const float*)d_in[17];
  const float* ln2_b    = (const float*)d_in[18];
  const float* cls_w    = (const float*)d_in[19];
  const float* cls_b    = (const float*)d_in[20];
  float* out = (float*)d_out;

  float* ws = (float*)d_ws;
  float* x     = ws;  ws += B * L * D;        // 262144
  float* q     = ws;  ws += B * L * D;
  float* kbuf  = ws;  ws += B * L * D;
  float* vbuf  = ws;  ws += B * L * D;
  float* o     = ws;  ws += B * L * D;
  float* tmp   = ws;  ws += B * L * D;
  float* ffn_h = ws;  ws += B * L * DFF;      // 1048576
  float* attn  = ws;  ws += (size_t)B * H * L * L;  // 4194304
  float* T     = ws;  ws += 2048;
  float* pbm   = ws;  ws += 8;

  const int M = B * L;  // 1024
  prep_kernel<<<1, 256, 0, stream>>>(pos_w, pos_b, T, pbm);

  // reduce layer: x = selu(feature @ w_reduce + b_reduce), K=400, N=256
  {
    dim3 grid(M / 8, D / 256);
    matmul_kernel<8><<<grid, 256, 8 * DIN * sizeof(float), stream>>>(
        feature, w_reduce, b_reduce, x, DIN, D, 2);
  }

  for (int l = 0; l < NL; ++l) {
    dim3 gdd(M / 8, D / 256);
    size_t shD = 8 * D * sizeof(float);
    matmul_kernel<8><<<gdd, 256, shD, stream>>>(x, wq + l * D * D, nullptr, q, D, D, 0);
    matmul_kernel<8><<<gdd, 256, shD, stream>>>(x, wk + l * D * D, nullptr, kbuf, D, D, 0);
    matmul_kernel<8><<<gdd, 256, shD, stream>>>(x, wv + l * D * D, nullptr, vbuf, D, D, 0);

    scores_softmax_kernel<<<B * H * L, 256, 0, stream>>>(q, kbuf, pos_ind,
                                                         fmaskp, T, pbm, attn);
    attn_v_kernel<<<M, 256, 0, stream>>>(attn, vbuf, o);

    matmul_kernel<8><<<gdd, 256, shD, stream>>>(o, wo + l * D * D, nullptr, tmp, D, D, 0);
    ln_residual_kernel<<<M, 256, 0, stream>>>(x, tmp, ln1_g + l * D, ln1_b + l * D, x);

    dim3 gff(M / 8, DFF / 256);
    matmul_kernel<8><<<gff, 256, shD, stream>>>(x, w1 + l * D * DFF, b1 + l * DFF,
                                                ffn_h, D, DFF, 1);
    matmul_kernel<8><<<gdd, 256, 8 * DFF * sizeof(float), stream>>>(
        ffn_h, w2 + l * DFF * D, b2 + l * D, tmp, DFF, D, 0);
    ln_residual_kernel<<<M, 256, 0, stream>>>(x, tmp, ln2_g + l * D, ln2_b + l * D, x);
  }

  cls_kernel<<<(M + 255) / 256, 256, 0, stream>>>(x, cls_w, cls_b, out);
}

// Round 2
// 403.317 us; speedup vs baseline: 1.4509x; 1.4509x over previous
//
#include <hip/hip_runtime.h>
#include <math.h>

#define B 2
#define L 512
#define DIN 400
#define D 256
#define H 8
#define DKK 32
#define DFF 1024
#define NL 2
#define NCLS 2

// ---------------------------------------------------------------------------
// prep: pwm[k][h] = mean_d pos_w[k, h*32+d]; pbm[h] = mean_d pos_b[h*32+d];
//       T[c*128 + (p+64)][h] = sum_r sin(p/dm[r])*pwm[c*128+r][h]
//                                    + cos(p/dm[r])*pwm[c*128+64+r][h]
// ---------------------------------------------------------------------------
__global__ void prep_kernel(const float* __restrict__ pos_w,
                            const float* __restrict__ pos_b,
                            float* __restrict__ T, float* __restrict__ pbm) {
  __shared__ float s_pwm[256 * 8];
  __shared__ float s_inv[64];
  int t = threadIdx.x;  // 256 threads
  {
    int k = t;
    for (int h = 0; h < 8; ++h) {
      float s = 0.f;
      for (int d = 0; d < DKK; ++d) s += pos_w[k * D + h * DKK + d];
      s_pwm[k * 8 + h] = s * (1.0f / DKK);
    }
  }
  if (t < 64) s_inv[t] = powf(10000.0f, -(float)t * (1.0f / 64.0f));
  if (t < 8) {
    float s = 0.f;
    for (int d = 0; d < DKK; ++d) s += pos_b[t * DKK + d];
    pbm[t] = s * (1.0f / DKK);
  }
  __syncthreads();
  int c = t >> 7;
  float p = (float)((t & 127) - 64);
  float acc[8] = {0, 0, 0, 0, 0, 0, 0, 0};
  for (int r = 0; r < 64; ++r) {
    float a = p * s_inv[r];
    float sv = sinf(a), cv = cosf(a);
    const float* ps = &s_pwm[(c * 128 + r) * 8];
    const float* pc = &s_pwm[(c * 128 + 64 + r) * 8];
#pragma unroll
    for (int h = 0; h < 8; ++h) acc[h] += sv * ps[h] + cv * pc[h];
  }
  for (int h = 0; h < 8; ++h) T[t * 8 + h] = acc[h];
}

// ---------------------------------------------------------------------------
// matmul: C[M,N] = act(A[M,K] @ W[K,N] + bias)
// block = 256 threads = 4 rows x 64 cols; grid (M/4, N/64)
// ACT: 0 none, 1 relu, 2 selu
// ---------------------------------------------------------------------------
template <int K, int ACT>
__global__ void mm_kernel(const float* __restrict__ A,
                          const float* __restrict__ W,
                          const float* __restrict__ bias,
                          float* __restrict__ C, int N) {
  __shared__ float arows[4 * K];
  int t = threadIdx.x;
  int row0 = blockIdx.x * 4;
  for (int e = t; e < 4 * K; e += 256) {
    int r = e / K, kk = e - r * K;
    arows[e] = A[(row0 + r) * K + kk];
  }
  __syncthreads();
  int r = t >> 6;
  int c = blockIdx.y * 64 + (t & 63);
  float acc = bias ? bias[c] : 0.0f;
  const float* a = &arows[r * K];
  const float* w = &W[c];
#pragma unroll 8
  for (int kk = 0; kk < K; ++kk) acc += a[kk] * w[kk * N];
  if (ACT == 1) acc = fmaxf(acc, 0.0f);
  else if (ACT == 2) {
    const float s_alpha = 1.6732632423543772f, s_scale = 1.0507009873554805f;
    acc = s_scale * (acc > 0.f ? acc : s_alpha * expm1f(acc));
  }
  C[(row0 + r) * N + c] = acc;
}

// ---------------------------------------------------------------------------
// fused QKV: grid (M/4, 12); blockIdx.y: [0..3]=Q cols, [4..7]=K, [8..11]=V
// ---------------------------------------------------------------------------
__global__ void qkv_kernel(const float* __restrict__ x,
                           const float* __restrict__ wq,
                           const float* __restrict__ wk,
                           const float* __restrict__ wv,
                           float* __restrict__ q, float* __restrict__ k,
                           float* __restrict__ v) {
  __shared__ float arows[4 * D];
  int t = threadIdx.x;
  int row0 = blockIdx.x * 4;
  for (int e = t; e < 4 * D; e += 256) {
    int r = e >> 8, kk = e & 255;
    arows[e] = x[(row0 + r) * D + kk];
  }
  __syncthreads();
  int wsel = blockIdx.y >> 2;
  int cg = blockIdx.y & 3;
  const float* W = wsel == 0 ? wq : wsel == 1 ? wk : wv;
  float* O = wsel == 0 ? q : wsel == 1 ? k : v;
  int r = t >> 6;
  int c = cg * 64 + (t & 63);
  float acc = 0.0f;
  const float* a = &arows[r * D];
  const float* w = &W[c];
#pragma unroll 8
  for (int kk = 0; kk < D; ++kk) acc += a[kk] * w[kk * D];
  O[(row0 + r) * D + c] = acc;
}

// ---------------------------------------------------------------------------
// fused scores + mask + pos-bias + softmax + PV
// block per (b,h,i): blockIdx.x = bh*512 + i; 256 threads
// ---------------------------------------------------------------------------
__global__ void attn_kernel(const float* __restrict__ q,
                            const float* __restrict__ k,
                            const float* __restrict__ v,
                            const float* __restrict__ pos_ind,
                            const float* __restrict__ fmask,
                            const float* __restrict__ T,
                            const float* __restrict__ pbm,
                            float* __restrict__ o) {
  __shared__ float sT[2048];
  __shared__ float qrow[DKK];
  __shared__ float red[256];
  __shared__ float p[512];
  __shared__ float po[8 * DKK];
  int t = threadIdx.x;
  int i = blockIdx.x & 511;
  int bh = blockIdx.x >> 9;
  int h = bh & 7, b = bh >> 3;
  for (int e = t; e < 2048; e += 256) sT[e] = T[e];
  if (t < DKK) qrow[t] = q[(b * L + i) * D + h * DKK + t];
  float fmi = fmask[b * L + i];
  float s_pbm = pbm[h];
  __syncthreads();
  const float scale = 0.17677669529663687f;  // 1/sqrt(32)
  float s[2];
#pragma unroll
  for (int u = 0; u < 2; ++u) {
    int j = t + u * 256;
    float fmj = fmask[b * L + j];
    bool aj = (1.0f - fmj) > 0.0f;
    bool ai = (1.0f - fmi) > 0.0f;
    int di = i - j;
    bool local_np = (di >= 9) || (di <= -8);
    int ad = di < 0 ? -di : di;
    bool dil_np = (ad & 15) != 0;
    bool m = (dil_np || aj || ai) && (local_np || aj);
    if (m) {
      s[u] = -1e9f;
    } else {
      const float* kr = &k[(b * L + j) * D + h * DKK];
      float dot = 0.f;
#pragma unroll
      for (int d = 0; d < DKK; ++d) dot += qrow[d] * kr[d];
      int pidx = ((b * L + i) * L + j) * 2;
      int p0 = (int)floorf(pos_ind[pidx]);
      int p1 = (int)floorf(pos_ind[pidx + 1]);
      p0 = min(max(p0, -64), 63);
      p1 = min(max(p1, -64), 63);
      float pb = sT[(p0 + 64) * 8 + h] + sT[(128 + p1 + 64) * 8 + h] + s_pbm;
      s[u] = dot * scale + pb;
    }
  }
  float mx = fmaxf(s[0], s[1]);
  red[t] = mx;
  __syncthreads();
  for (int w = 128; w > 0; w >>= 1) {
    if (t < w) red[t] = fmaxf(red[t], red[t + w]);
    __syncthreads();
  }
  mx = red[0];
  __syncthreads();
  float e0 = expf(s[0] - mx), e1 = expf(s[1] - mx);
  red[t] = e0 + e1;
  __syncthreads();
  for (int w = 128; w > 0; w >>= 1) {
    if (t < w) red[t] += red[t + w];
    __syncthreads();
  }
  float inv = 1.0f / red[0];
  p[t] = e0 * inv;
  p[t + 256] = e1 * inv;
  __syncthreads();
  // PV: 8 groups x 32 d
  int d = t & 31, g = t >> 5;
  const float* vb = &v[(b * L + g * 64) * D + h * DKK + d];
  const float* pg = &p[g * 64];
  float acc = 0.f;
#pragma unroll 8
  for (int jj = 0; jj < 64; ++jj) acc += pg[jj] * vb[jj * D];
  po[g * DKK + d] = acc;
  __syncthreads();
  if (t < DKK) {
    float sum = 0.f;
#pragma unroll
    for (int g2 = 0; g2 < 8; ++g2) sum += po[g2 * DKK + t];
    o[(b * L + i) * D + h * DKK + t] = sum;
  }
}

// ---------------------------------------------------------------------------
// x = LayerNorm(resid + y) * g + b   (block per row, 256 threads = D)
// ---------------------------------------------------------------------------
__global__ void ln_residual_kernel(const float* __restrict__ resid,
                                   const float* __restrict__ y,
                                   const float* __restrict__ g,
                                   const float* __restrict__ bta,
                                   float* __restrict__ outx) {
  __shared__ float red[256];
  int row = blockIdx.x;
  int t = threadIdx.x;
  float val = resid[row * D + t] + y[row * D + t];
  red[t] = val;
  __syncthreads();
  for (int w = 128; w > 0; w >>= 1) {
    if (t < w) red[t] += red[t + w];
    __syncthreads();
  }
  float mean = red[0] * (1.0f / D);
  __syncthreads();
  float diff = val - mean;
  red[t] = diff * diff;
  __syncthreads();
  for (int w = 128; w > 0; w >>= 1) {
    if (t < w) red[t] += red[t + w];
    __syncthreads();
  }
  float var = red[0] * (1.0f / D);
  float rs = rsqrtf(var + 1e-5f);
  outx[row * D + t] = diff * rs * g[t] + bta[t];
}

// ---------------------------------------------------------------------------
// final: LN2 + classifier + 2-way softmax fused (block per row)
// ---------------------------------------------------------------------------
__global__ void ln_res_cls_kernel(const float* __restrict__ resid,
                                  const float* __restrict__ y,
                                  const float* __restrict__ g,
                                  const float* __restrict__ bta,
                                  const float* __restrict__ cw,
                                  const float* __restrict__ cb,
                                  float* __restrict__ out) {
  __shared__ float red[256];
  int row = blockIdx.x;
  int t = threadIdx.x;
  float val = resid[row * D + t] + y[row * D + t];
  red[t] = val;
  __syncthreads();
  for (int w = 128; w > 0; w >>= 1) {
    if (t < w) red[t] += red[t + w];
    __syncthreads();
  }
  float mean = red[0] * (1.0f / D);
  __syncthreads();
  float diff = val - mean;
  red[t] = diff * diff;
  __syncthreads();
  for (int w = 128; w > 0; w >>= 1) {
    if (t < w) red[t] += red[t + w];
    __syncthreads();
  }
  float var = red[0] * (1.0f / D);
  float rs = rsqrtf(var + 1e-5f);
  float xv = diff * rs * g[t] + bta[t];
  __syncthreads();
  red[t] = xv * cw[t * NCLS + 0];
  __syncthreads();
  for (int w = 128; w > 0; w >>= 1) {
    if (t < w) red[t] += red[t + w];
    __syncthreads();
  }
  float l0 = red[0] + cb[0];
  __syncthreads();
  red[t] = xv * cw[t * NCLS + 1];
  __syncthreads();
  for (int w = 128; w > 0; w >>= 1) {
    if (t < w) red[t] += red[t + w];
    __syncthreads();
  }
  float l1 = red[0] + cb[1];
  if (t == 0) {
    float mx = fmaxf(l0, l1);
    float e0 = expf(l0 - mx), e1 = expf(l1 - mx);
    float inv = 1.0f / (e0 + e1);
    out[row * 2 + 0] = e0 * inv;
    out[row * 2 + 1] = e1 * inv;
  }
}

extern "C" void kernel_launch(void* const* d_in, const int* in_sizes, int n_in,
                              void* d_out, int out_size, void* d_ws,
                              size_t ws_size, hipStream_t stream) {
  const float* feature  = (const float*)d_in[0];
  const float* pos_ind  = (const float*)d_in[1];
  const float* fmaskp   = (const float*)d_in[2];
  const float* w_reduce = (const float*)d_in[3];
  const float* b_reduce = (const float*)d_in[4];
  const float* pos_w    = (const float*)d_in[5];
  const float* pos_b    = (const float*)d_in[6];
  const float* wq       = (const float*)d_in[7];
  const float* wk       = (const float*)d_in[8];
  const float* wv       = (const float*)d_in[9];
  const float* wo       = (const float*)d_in[10];
  const float* ln1_g    = (const float*)d_in[11];
  const float* ln1_b    = (const float*)d_in[12];
  const float* w1       = (const float*)d_in[13];
  const float* b1       = (const float*)d_in[14];
  const float* w2       = (const float*)d_in[15];
  const float* b2       = (const float*)d_in[16];
  const float* ln2_g    = (const float*)d_in[17];
  const float* ln2_b    = (const float*)d_in[18];
  const float* cls_w    = (const float*)d_in[19];
  const float* cls_b    = (const float*)d_in[20];
  float* out = (float*)d_out;

  float* ws = (float*)d_ws;
  float* x     = ws;  ws += B * L * D;
  float* q     = ws;  ws += B * L * D;
  float* kbuf  = ws;  ws += B * L * D;
  float* vbuf  = ws;  ws += B * L * D;
  float* o     = ws;  ws += B * L * D;
  float* tmp   = ws;  ws += B * L * D;
  float* ffn_h = ws;  ws += B * L * DFF;
  float* T     = ws;  ws += 2048;
  float* pbm   = ws;  ws += 8;

  const int M = B * L;  // 1024
  prep_kernel<<<1, 256, 0, stream>>>(pos_w, pos_b, T, pbm);

  // reduce layer: x = selu(feature @ w_reduce + b_reduce), K=400, N=256
  mm_kernel<DIN, 2><<<dim3(M / 4, D / 64), 256, 0, stream>>>(
      feature, w_reduce, b_reduce, x, D);

  for (int l = 0; l < NL; ++l) {
    qkv_kernel<<<dim3(M / 4, 12), 256, 0, stream>>>(
        x, wq + l * D * D, wk + l * D * D, wv + l * D * D, q, kbuf, vbuf);

    attn_kernel<<<B * H * L, 256, 0, stream>>>(q, kbuf, vbuf, pos_ind, fmaskp,
                                               T, pbm, o);

    mm_kernel<D, 0><<<dim3(M / 4, D / 64), 256, 0, stream>>>(
        o, wo + l * D * D, nullptr, tmp, D);
    ln_residual_kernel<<<M, 256, 0, stream>>>(x, tmp, ln1_g + l * D,
                                              ln1_b + l * D, x);

    mm_kernel<D, 1><<<dim3(M / 4, DFF / 64), 256, 0, stream>>>(
        x, w1 + l * D * DFF, b1 + l * DFF, ffn_h, DFF);
    mm_kernel<DFF, 0><<<dim3(M / 4, D / 64), 256, 0, stream>>>(
        ffn_h, w2 + l * DFF * D, b2 + l * D, tmp, D);

    if (l == NL - 1) {
      ln_res_cls_kernel<<<M, 256, 0, stream>>>(x, tmp, ln2_g + l * D,
                                               ln2_b + l * D, cls_w, cls_b, out);
    } else {
      ln_residual_kernel<<<M, 256, 0, stream>>>(x, tmp, ln2_g + l * D,
                                                ln2_b + l * D, x);
    }
  }
}

// Round 3
// 255.061 us; speedup vs baseline: 2.2942x; 1.5813x over previous
//
#include <hip/hip_runtime.h>
#include <math.h>

#define B 2
#define L 512
#define DIN 400
#define D 256
#define H 8
#define DKK 32
#define DFF 1024
#define NL 2
#define NCLS 2

// ---------------------------------------------------------------------------
// prep: pwm[k][h] = mean_d pos_w[k, h*32+d]; pbm[h] = mean_d pos_b[h*32+d];
//       T[c*128 + (p+64)][h] = sum_r sin(p*s_inv[r])*pwm[c*128+r][h]
//                                    + cos(p*s_inv[r])*pwm[c*128+64+r][h]
// ---------------------------------------------------------------------------
__global__ void prep_kernel(const float* __restrict__ pos_w,
                            const float* __restrict__ pos_b,
                            float* __restrict__ T, float* __restrict__ pbm) {
  __shared__ float s_pwm[256 * 8];
  __shared__ float s_inv[64];
  int t = threadIdx.x;  // 256 threads
  {
    int k = t;
    for (int h = 0; h < 8; ++h) {
      float s = 0.f;
      for (int d = 0; d < DKK; ++d) s += pos_w[k * D + h * DKK + d];
      s_pwm[k * 8 + h] = s * (1.0f / DKK);
    }
  }
  if (t < 64) s_inv[t] = powf(10000.0f, -(float)t * (1.0f / 64.0f));
  if (t < 8) {
    float s = 0.f;
    for (int d = 0; d < DKK; ++d) s += pos_b[t * DKK + d];
    pbm[t] = s * (1.0f / DKK);
  }
  __syncthreads();
  int c = t >> 7;
  float p = (float)((t & 127) - 64);
  float acc[8] = {0, 0, 0, 0, 0, 0, 0, 0};
  for (int r = 0; r < 64; ++r) {
    float a = p * s_inv[r];
    float sv = sinf(a), cv = cosf(a);
    const float* ps = &s_pwm[(c * 128 + r) * 8];
    const float* pc = &s_pwm[(c * 128 + 64 + r) * 8];
#pragma unroll
    for (int h = 0; h < 8; ++h) acc[h] += sv * ps[h] + cv * pc[h];
  }
  for (int h = 0; h < 8; ++h) T[t * 8 + h] = acc[h];
}

// ---------------------------------------------------------------------------
// register-tiled GEMM: C = act(A[M,K] @ W[K,N] + bias)
// BM=32, BN=64, BK=16; 256 threads; micro-tile TM=2 x TN=4.
// MODE 0: single matrix. MODE 1: blockIdx.z selects (Wa,Ca)/(Wb,Cb)/(Wc,Cc).
// MODE 2: split-K in 2 halves; z=0 -> Ca (with bias), z=1 -> Cb (no bias).
// ACT: 0 none, 1 relu, 2 selu
// ---------------------------------------------------------------------------
template <int BM, int BN, int BK, int TM, int TN, int ACT, int MODE>
__global__ __launch_bounds__(256) void gemm_kernel(
    const float* __restrict__ A, const float* __restrict__ Wa,
    const float* __restrict__ Wb, const float* __restrict__ Wc,
    const float* __restrict__ bias, float* __restrict__ Ca,
    float* __restrict__ Cb, float* __restrict__ Cc, int M, int N, int K) {
  constexpr int TCOLS = BN / TN;
  constexpr int TROWS = BM / TM;
  static_assert(TCOLS * TROWS == 256, "need 256 threads");
  __shared__ float As[BK][BM + 4];
  __shared__ float Bs[BK][BN + 4];
  int tid = threadIdx.x;
  int m0 = blockIdx.x * BM;
  int n0 = blockIdx.y * BN;
  const float* W = Wa;
  float* C = Ca;
  int kBeg = 0, kEnd = K;
  bool useBias = (bias != nullptr);
  if (MODE == 1) {
    W = blockIdx.z == 0 ? Wa : (blockIdx.z == 1 ? Wb : Wc);
    C = blockIdx.z == 0 ? Ca : (blockIdx.z == 1 ? Cb : Cc);
  } else if (MODE == 2) {
    int half = K / 2;
    kBeg = blockIdx.z * half;
    kEnd = kBeg + half;
    C = blockIdx.z == 0 ? Ca : Cb;
    if (blockIdx.z != 0) useBias = false;
  }
  int tc = tid % TCOLS;
  int tr = tid / TCOLS;
  float acc[TM][TN];
  float bb[TN];
#pragma unroll
  for (int j = 0; j < TN; ++j)
    bb[j] = useBias ? bias[n0 + tc * TN + j] : 0.0f;
#pragma unroll
  for (int i = 0; i < TM; ++i)
#pragma unroll
    for (int j = 0; j < TN; ++j) acc[i][j] = 0.0f;

  for (int k0 = kBeg; k0 < kEnd; k0 += BK) {
    for (int e = tid; e < BM * BK / 4; e += 256) {
      int arow = e / (BK / 4);
      int kq = e % (BK / 4);
      const float4 v =
          *(const float4*)&A[(size_t)(m0 + arow) * K + k0 + kq * 4];
      As[kq * 4 + 0][arow] = v.x;
      As[kq * 4 + 1][arow] = v.y;
      As[kq * 4 + 2][arow] = v.z;
      As[kq * 4 + 3][arow] = v.w;
    }
    for (int e = tid; e < BK * BN / 4; e += 256) {
      int brow = e / (BN / 4);
      int nq = e % (BN / 4);
      *(float4*)&Bs[brow][nq * 4] =
          *(const float4*)&W[(size_t)(k0 + brow) * N + n0 + nq * 4];
    }
    __syncthreads();
#pragma unroll
    for (int k = 0; k < BK; ++k) {
      float a[TM], b[TN];
#pragma unroll
      for (int i = 0; i < TM; ++i) a[i] = As[k][tr * TM + i];
#pragma unroll
      for (int j = 0; j < TN; ++j) b[j] = Bs[k][tc * TN + j];
#pragma unroll
      for (int i = 0; i < TM; ++i)
#pragma unroll
        for (int j = 0; j < TN; ++j) acc[i][j] += a[i] * b[j];
    }
    __syncthreads();
  }
  const float s_alpha = 1.6732632423543772f, s_scale = 1.0507009873554805f;
#pragma unroll
  for (int i = 0; i < TM; ++i) {
    int row = m0 + tr * TM + i;
    float4 outv;
    float tmp4[4];
#pragma unroll
    for (int j = 0; j < TN; ++j) {
      float v = acc[i][j] + bb[j];
      if (ACT == 1) v = fmaxf(v, 0.0f);
      else if (ACT == 2) v = s_scale * (v > 0.f ? v : s_alpha * expm1f(v));
      tmp4[j] = v;
    }
    outv.x = tmp4[0]; outv.y = tmp4[1]; outv.z = tmp4[2]; outv.w = tmp4[3];
    *(float4*)&C[(size_t)row * N + n0 + tc * TN] = outv;
  }
}

// ---------------------------------------------------------------------------
// sparse attention: block per (b,i), 512 threads = 8 waves (one per head).
// Compact unmasked j-list (<=47 entries) deterministically, then per-head
// wave-level scores+softmax+PV.
// ---------------------------------------------------------------------------
__global__ __launch_bounds__(512) void attn_kernel(
    const float* __restrict__ q, const float* __restrict__ k,
    const float* __restrict__ v, const float* __restrict__ pos_ind,
    const float* __restrict__ fmask, const float* __restrict__ T,
    const float* __restrict__ pbm, float* __restrict__ o) {
  __shared__ float sT[2048];
  __shared__ float qrow[256];
  __shared__ float psh[8][64];
  __shared__ int jlist[64];
  __shared__ int p0s[64];
  __shared__ int p1s[64];
  __shared__ int wcnt[8];
  __shared__ int woff[8];
  __shared__ int njs;
  int t = threadIdx.x;
  int bi = blockIdx.x;  // b*L + i
  int b = bi >> 9, i = bi & 511;
  for (int e = t; e < 2048; e += 512) sT[e] = T[e];
  if (t < 256) qrow[t] = q[(size_t)bi * D + t];
  float fmi = fmask[bi];
  __syncthreads();
  // --- deterministic compaction of unmasked j ---
  {
    int j = t;
    float fmj = fmask[b * L + j];
    bool aj = (1.0f - fmj) > 0.0f;
    bool ai = (1.0f - fmi) > 0.0f;
    int di = i - j;
    bool local_np = (di >= 9) || (di <= -8);
    int ad = di < 0 ? -di : di;
    bool dil_np = (ad & 15) != 0;
    bool m = (dil_np || aj || ai) && (local_np || aj);
    unsigned long long ball = __ballot(!m);
    int wv = t >> 6;
    if ((t & 63) == 0) wcnt[wv] = __popcll(ball);
    __syncthreads();
    if (t == 0) {
      int s = 0;
      for (int w = 0; w < 8; ++w) { woff[w] = s; s += wcnt[w]; }
      njs = s;
    }
    __syncthreads();
    if (!m) {
      int slot = woff[wv] +
                 __popcll(ball & ((1ull << (unsigned)(t & 63)) - 1ull));
      jlist[slot] = j;
      int pidx = ((size_t)bi * L + j) * 2;
      int p0 = (int)floorf(pos_ind[pidx]);
      int p1 = (int)floorf(pos_ind[pidx + 1]);
      p0s[slot] = min(max(p0, -64), 63) + 64;
      p1s[slot] = min(max(p1, -64), 63) + 192;
    }
  }
  __syncthreads();
  int nj = njs;
  int h = t >> 6, sl = t & 63;
  if (nj > 0) {
    float sc = -1e30f;
    if (sl < nj) {
      int j = jlist[sl];
      const float4* kr4 = (const float4*)&k[(size_t)(b * L + j) * D + h * 32];
      const float4* qh4 = (const float4*)&qrow[h * 32];
      float dot = 0.f;
#pragma unroll
      for (int dq = 0; dq < 8; ++dq) {
        float4 a = qh4[dq], b2 = kr4[dq];
        dot += a.x * b2.x + a.y * b2.y + a.z * b2.z + a.w * b2.w;
      }
      sc = dot * 0.17677669529663687f + sT[p0s[sl] * 8 + h] +
           sT[p1s[sl] * 8 + h] + pbm[h];
    }
    float mx = sc;
#pragma unroll
    for (int m2 = 32; m2; m2 >>= 1) mx = fmaxf(mx, __shfl_xor(mx, m2));
    float e = (sl < nj) ? expf(sc - mx) : 0.0f;
    float ssum = e;
#pragma unroll
    for (int m2 = 32; m2; m2 >>= 1) ssum += __shfl_xor(ssum, m2);
    psh[h][sl] = e / ssum;
  }
  __syncthreads();
  // --- PV over compact list ---
  int d = t & 31, half = (t >> 5) & 1;
  float acc = 0.f;
  if (nj > 0) {
    for (int s2 = half; s2 < nj; s2 += 2) {
      int j = jlist[s2];
      acc += psh[h][s2] * v[(size_t)(b * L + j) * D + h * 32 + d];
    }
  } else {
    // reference: softmax over all -1e9 -> uniform over all 512 keys
    for (int j = half; j < L; j += 2)
      acc += v[(size_t)(b * L + j) * D + h * 32 + d];
    acc *= (1.0f / L);
  }
  acc += __shfl_xor(acc, 32);
  if (half == 0) o[(size_t)bi * D + h * 32 + d] = acc;
}

// ---------------------------------------------------------------------------
// x = LayerNorm(resid + y0 + y1) * g + b  — one wave per row, 4 rows/block
// ---------------------------------------------------------------------------
__global__ __launch_bounds__(256) void ln3_kernel(
    const float* __restrict__ resid, const float* __restrict__ y0,
    const float* __restrict__ y1, const float* __restrict__ g,
    const float* __restrict__ bta, float* __restrict__ outx) {
  int t = threadIdx.x;
  int lane = t & 63;
  int row = blockIdx.x * 4 + (t >> 6);
  int base = row * D + lane * 4;
  float4 r = *(const float4*)&resid[base];
  float4 a = *(const float4*)&y0[base];
  float4 c = *(const float4*)&y1[base];
  float val[4] = {r.x + a.x + c.x, r.y + a.y + c.y, r.z + a.z + c.z,
                  r.w + a.w + c.w};
  float s = val[0] + val[1] + val[2] + val[3];
#pragma unroll
  for (int m = 32; m; m >>= 1) s += __shfl_xor(s, m);
  float mean = s * (1.0f / D);
  float vv = 0.f;
#pragma unroll
  for (int e = 0; e < 4; ++e) {
    float dd = val[e] - mean;
    vv += dd * dd;
  }
#pragma unroll
  for (int m = 32; m; m >>= 1) vv += __shfl_xor(vv, m);
  float rs = rsqrtf(vv * (1.0f / D) + 1e-5f);
  float4 gv = *(const float4*)&g[lane * 4];
  float4 bv = *(const float4*)&bta[lane * 4];
  float4 ov;
  ov.x = (val[0] - mean) * rs * gv.x + bv.x;
  ov.y = (val[1] - mean) * rs * gv.y + bv.y;
  ov.z = (val[2] - mean) * rs * gv.z + bv.z;
  ov.w = (val[3] - mean) * rs * gv.w + bv.w;
  *(float4*)&outx[base] = ov;
}

// ---------------------------------------------------------------------------
// final: LN2(resid+y0+y1) + classifier + 2-way softmax — one wave per row
// ---------------------------------------------------------------------------
__global__ __launch_bounds__(256) void ln_cls_kernel(
    const float* __restrict__ resid, const float* __restrict__ y0,
    const float* __restrict__ y1, const float* __restrict__ g,
    const float* __restrict__ bta, const float* __restrict__ cw,
    const float* __restrict__ cb, float* __restrict__ out) {
  int t = threadIdx.x;
  int lane = t & 63;
  int row = blockIdx.x * 4 + (t >> 6);
  int base = row * D + lane * 4;
  float4 r = *(const float4*)&resid[base];
  float4 a = *(const float4*)&y0[base];
  float4 c = *(const float4*)&y1[base];
  float val[4] = {r.x + a.x + c.x, r.y + a.y + c.y, r.z + a.z + c.z,
                  r.w + a.w + c.w};
  float s = val[0] + val[1] + val[2] + val[3];
#pragma unroll
  for (int m = 32; m; m >>= 1) s += __shfl_xor(s, m);
  float mean = s * (1.0f / D);
  float vv = 0.f;
#pragma unroll
  for (int e = 0; e < 4; ++e) {
    float dd = val[e] - mean;
    vv += dd * dd;
  }
#pragma unroll
  for (int m = 32; m; m >>= 1) vv += __shfl_xor(vv, m);
  float rs = rsqrtf(vv * (1.0f / D) + 1e-5f);
  float4 gv = *(const float4*)&g[lane * 4];
  float4 bv = *(const float4*)&bta[lane * 4];
  float xv[4];
  xv[0] = (val[0] - mean) * rs * gv.x + bv.x;
  xv[1] = (val[1] - mean) * rs * gv.y + bv.y;
  xv[2] = (val[2] - mean) * rs * gv.z + bv.z;
  xv[3] = (val[3] - mean) * rs * gv.w + bv.w;
  float l0 = 0.f, l1 = 0.f;
#pragma unroll
  for (int e = 0; e < 4; ++e) {
    int col = lane * 4 + e;
    l0 += xv[e] * cw[col * NCLS + 0];
    l1 += xv[e] * cw[col * NCLS + 1];
  }
#pragma unroll
  for (int m = 32; m; m >>= 1) {
    l0 += __shfl_xor(l0, m);
    l1 += __shfl_xor(l1, m);
  }
  if (lane == 0) {
    l0 += cb[0];
    l1 += cb[1];
    float mx = fmaxf(l0, l1);
    float e0 = expf(l0 - mx), e1 = expf(l1 - mx);
    float inv = 1.0f / (e0 + e1);
    out[row * 2 + 0] = e0 * inv;
    out[row * 2 + 1] = e1 * inv;
  }
}

extern "C" void kernel_launch(void* const* d_in, const int* in_sizes, int n_in,
                              void* d_out, int out_size, void* d_ws,
                              size_t ws_size, hipStream_t stream) {
  const float* feature  = (const float*)d_in[0];
  const float* pos_ind  = (const float*)d_in[1];
  const float* fmaskp   = (const float*)d_in[2];
  const float* w_reduce = (const float*)d_in[3];
  const float* b_reduce = (const float*)d_in[4];
  const float* pos_w    = (const float*)d_in[5];
  const float* pos_b    = (const float*)d_in[6];
  const float* wq       = (const float*)d_in[7];
  const float* wk       = (const float*)d_in[8];
  const float* wv       = (const float*)d_in[9];
  const float* wo       = (const float*)d_in[10];
  const float* ln1_g    = (const float*)d_in[11];
  const float* ln1_b    = (const float*)d_in[12];
  const float* w1       = (const float*)d_in[13];
  const float* b1       = (const float*)d_in[14];
  const float* w2       = (const float*)d_in[15];
  const float* b2       = (const float*)d_in[16];
  const float* ln2_g    = (const float*)d_in[17];
  const float* ln2_b    = (const float*)d_in[18];
  const float* cls_w    = (const float*)d_in[19];
  const float* cls_b    = (const float*)d_in[20];
  float* out = (float*)d_out;

  float* ws = (float*)d_ws;
  float* x     = ws;  ws += B * L * D;
  float* q     = ws;  ws += B * L * D;
  float* kbuf  = ws;  ws += B * L * D;
  float* vbuf  = ws;  ws += B * L * D;
  float* o     = ws;  ws += B * L * D;
  float* tmp   = ws;  ws += B * L * D;
  float* tmp2  = ws;  ws += B * L * D;
  float* ffn_h = ws;  ws += B * L * DFF;
  float* T     = ws;  ws += 2048;
  float* pbm   = ws;  ws += 8;

  const int M = B * L;  // 1024
  prep_kernel<<<1, 256, 0, stream>>>(pos_w, pos_b, T, pbm);

  // reduce layer: x = selu(feature @ w_reduce + b_reduce)
  gemm_kernel<32, 64, 16, 2, 4, 2, 0><<<dim3(M / 32, D / 64), 256, 0, stream>>>(
      feature, w_reduce, nullptr, nullptr, b_reduce, x, nullptr, nullptr,
      M, D, DIN);

  for (int l = 0; l < NL; ++l) {
    // fused QKV (z selects matrix)
    gemm_kernel<32, 64, 16, 2, 4, 0, 1>
        <<<dim3(M / 32, D / 64, 3), 256, 0, stream>>>(
            x, wq + l * D * D, wk + l * D * D, wv + l * D * D, nullptr,
            q, kbuf, vbuf, M, D, D);

    attn_kernel<<<M, 512, 0, stream>>>(q, kbuf, vbuf, pos_ind, fmaskp, T, pbm,
                                       o);

    // wo projection, split-K
    gemm_kernel<32, 64, 16, 2, 4, 0, 2>
        <<<dim3(M / 32, D / 64, 2), 256, 0, stream>>>(
            o, wo + l * D * D, nullptr, nullptr, nullptr, tmp, tmp2, nullptr,
            M, D, D);
    ln3_kernel<<<M / 4, 256, 0, stream>>>(x, tmp, tmp2, ln1_g + l * D,
                                          ln1_b + l * D, x);

    // FFN up (relu)
    gemm_kernel<32, 64, 16, 2, 4, 1, 0>
        <<<dim3(M / 32, DFF / 64), 256, 0, stream>>>(
            x, w1 + l * D * DFF, nullptr, nullptr, b1 + l * DFF, ffn_h,
            nullptr, nullptr, M, DFF, D);
    // FFN down, split-K
    gemm_kernel<32, 64, 16, 2, 4, 0, 2>
        <<<dim3(M / 32, D / 64, 2), 256, 0, stream>>>(
            ffn_h, w2 + l * DFF * D, nullptr, nullptr, b2 + l * D, tmp, tmp2,
            nullptr, M, D, DFF);

    if (l == NL - 1) {
      ln_cls_kernel<<<M / 4, 256, 0, stream>>>(x, tmp, tmp2, ln2_g + l * D,
                                               ln2_b + l * D, cls_w, cls_b,
                                               out);
    } else {
      ln3_kernel<<<M / 4, 256, 0, stream>>>(x, tmp, tmp2, ln2_g + l * D,
                                            ln2_b + l * D, x);
    }
  }
}

// Round 4
// 236.450 us; speedup vs baseline: 2.4748x; 1.0787x over previous
//
#include <hip/hip_runtime.h>
#include <math.h>

#define B 2
#define L 512
#define DIN 400
#define D 256
#define H 8
#define DKK 32
#define DFF 1024
#define NL 2
#define NCLS 2

// ---------------------------------------------------------------------------
// register-tiled GEMM: C = act(A[M,K] @ W[K,N] + bias)
// 256 threads; micro-tile TM x TN; block tile BM x BN, K-step BK.
// MODE 0: single matrix. MODE 1: blockIdx.z selects (Wa,Ca)/(Wb,Cb)/(Wc,Cc).
// MODE 2: split-K in 2 halves; z=0 -> Ca (with bias), z=1 -> Cb (no bias).
// ACT: 0 none, 1 relu, 2 selu
// ---------------------------------------------------------------------------
template <int BM, int BN, int BK, int TM, int TN, int ACT, int MODE>
__global__ __launch_bounds__(256) void gemm_kernel(
    const float* __restrict__ A, const float* __restrict__ Wa,
    const float* __restrict__ Wb, const float* __restrict__ Wc,
    const float* __restrict__ bias, float* __restrict__ Ca,
    float* __restrict__ Cb, float* __restrict__ Cc, int M, int N, int K) {
  constexpr int TCOLS = BN / TN;
  constexpr int TROWS = BM / TM;
  static_assert(TCOLS * TROWS == 256, "need 256 threads");
  __shared__ float As[BK][BM + 4];
  __shared__ float Bs[BK][BN + 4];
  int tid = threadIdx.x;
  int m0 = blockIdx.x * BM;
  int n0 = blockIdx.y * BN;
  const float* W = Wa;
  float* C = Ca;
  int kBeg = 0, kEnd = K;
  bool useBias = (bias != nullptr);
  if (MODE == 1) {
    W = blockIdx.z == 0 ? Wa : (blockIdx.z == 1 ? Wb : Wc);
    C = blockIdx.z == 0 ? Ca : (blockIdx.z == 1 ? Cb : Cc);
  } else if (MODE == 2) {
    int half = K / 2;
    kBeg = blockIdx.z * half;
    kEnd = kBeg + half;
    C = blockIdx.z == 0 ? Ca : Cb;
    if (blockIdx.z != 0) useBias = false;
  }
  int tc = tid % TCOLS;
  int tr = tid / TCOLS;
  float acc[TM][TN];
  float bb[TN];
#pragma unroll
  for (int j = 0; j < TN; ++j)
    bb[j] = useBias ? bias[n0 + tc * TN + j] : 0.0f;
#pragma unroll
  for (int i = 0; i < TM; ++i)
#pragma unroll
    for (int j = 0; j < TN; ++j) acc[i][j] = 0.0f;

  for (int k0 = kBeg; k0 < kEnd; k0 += BK) {
    for (int e = tid; e < BM * BK / 4; e += 256) {
      int arow = e / (BK / 4);
      int kq = e % (BK / 4);
      const float4 v =
          *(const float4*)&A[(size_t)(m0 + arow) * K + k0 + kq * 4];
      As[kq * 4 + 0][arow] = v.x;
      As[kq * 4 + 1][arow] = v.y;
      As[kq * 4 + 2][arow] = v.z;
      As[kq * 4 + 3][arow] = v.w;
    }
    for (int e = tid; e < BK * BN / 4; e += 256) {
      int brow = e / (BN / 4);
      int nq = e % (BN / 4);
      *(float4*)&Bs[brow][nq * 4] =
          *(const float4*)&W[(size_t)(k0 + brow) * N + n0 + nq * 4];
    }
    __syncthreads();
#pragma unroll
    for (int k = 0; k < BK; ++k) {
      float a[TM], b[TN];
#pragma unroll
      for (int i = 0; i < TM; ++i) a[i] = As[k][tr * TM + i];
#pragma unroll
      for (int j = 0; j < TN; ++j) b[j] = Bs[k][tc * TN + j];
#pragma unroll
      for (int i = 0; i < TM; ++i)
#pragma unroll
        for (int j = 0; j < TN; ++j) acc[i][j] += a[i] * b[j];
    }
    __syncthreads();
  }
  const float s_alpha = 1.6732632423543772f, s_scale = 1.0507009873554805f;
#pragma unroll
  for (int i = 0; i < TM; ++i) {
    int row = m0 + tr * TM + i;
#pragma unroll
    for (int jq = 0; jq < TN / 4; ++jq) {
      float4 outv;
      float tmp4[4];
#pragma unroll
      for (int j = 0; j < 4; ++j) {
        float v = acc[i][jq * 4 + j] + bb[jq * 4 + j];
        if (ACT == 1) v = fmaxf(v, 0.0f);
        else if (ACT == 2) v = s_scale * (v > 0.f ? v : s_alpha * expm1f(v));
        tmp4[j] = v;
      }
      outv.x = tmp4[0]; outv.y = tmp4[1]; outv.z = tmp4[2]; outv.w = tmp4[3];
      *(float4*)&C[(size_t)row * N + n0 + tc * TN + jq * 4] = outv;
    }
  }
}

// ---------------------------------------------------------------------------
// reduce layer GEMM (selu(feature @ w_reduce + b)) with prep fused in as the
// last grid.x block (y==0): builds pos-bias table T[2048], pbm[8].
// ---------------------------------------------------------------------------
__global__ __launch_bounds__(256) void reduce_prep_kernel(
    const float* __restrict__ A, const float* __restrict__ W,
    const float* __restrict__ bias, float* __restrict__ C,
    const float* __restrict__ pos_w, const float* __restrict__ pos_b,
    float* __restrict__ T, float* __restrict__ pbm) {
  constexpr int BM = 32, BN = 64, BK = 16, TM = 2, TN = 4;
  constexpr int K = DIN, N = D;
  __shared__ union U {
    struct { float As[BK][BM + 4]; float Bs[BK][BN + 4]; } g;
    struct { float pwm[256 * 8]; float inv[64]; } p;
  } sh;
  int tid = threadIdx.x;
  if (blockIdx.x == gridDim.x - 1) {
    if (blockIdx.y != 0) return;
    // ---- prep body ----
    {
      int k = tid;
      for (int h = 0; h < 8; ++h) {
        float s = 0.f;
        for (int d = 0; d < DKK; ++d) s += pos_w[k * D + h * DKK + d];
        sh.p.pwm[k * 8 + h] = s * (1.0f / DKK);
      }
    }
    if (tid < 64) sh.p.inv[tid] = powf(10000.0f, -(float)tid * (1.0f / 64.0f));
    if (tid < 8) {
      float s = 0.f;
      for (int d = 0; d < DKK; ++d) s += pos_b[tid * DKK + d];
      pbm[tid] = s * (1.0f / DKK);
    }
    __syncthreads();
    int c = tid >> 7;
    float p = (float)((tid & 127) - 64);
    float acc[8] = {0, 0, 0, 0, 0, 0, 0, 0};
    for (int r = 0; r < 64; ++r) {
      float a = p * sh.p.inv[r];
      float sv = sinf(a), cv = cosf(a);
      const float* ps = &sh.p.pwm[(c * 128 + r) * 8];
      const float* pc = &sh.p.pwm[(c * 128 + 64 + r) * 8];
#pragma unroll
      for (int h = 0; h < 8; ++h) acc[h] += sv * ps[h] + cv * pc[h];
    }
    for (int h = 0; h < 8; ++h) T[tid * 8 + h] = acc[h];
    return;
  }
  // ---- gemm body ----
  int m0 = blockIdx.x * BM;
  int n0 = blockIdx.y * BN;
  int tc = tid % (BN / TN);
  int tr = tid / (BN / TN);
  float acc[TM][TN];
  float bb[TN];
#pragma unroll
  for (int j = 0; j < TN; ++j) bb[j] = bias[n0 + tc * TN + j];
#pragma unroll
  for (int i = 0; i < TM; ++i)
#pragma unroll
    for (int j = 0; j < TN; ++j) acc[i][j] = 0.0f;
  for (int k0 = 0; k0 < K; k0 += BK) {
    for (int e = tid; e < BM * BK / 4; e += 256) {
      int arow = e / (BK / 4);
      int kq = e % (BK / 4);
      const float4 v =
          *(const float4*)&A[(size_t)(m0 + arow) * K + k0 + kq * 4];
      sh.g.As[kq * 4 + 0][arow] = v.x;
      sh.g.As[kq * 4 + 1][arow] = v.y;
      sh.g.As[kq * 4 + 2][arow] = v.z;
      sh.g.As[kq * 4 + 3][arow] = v.w;
    }
    for (int e = tid; e < BK * BN / 4; e += 256) {
      int brow = e / (BN / 4);
      int nq = e % (BN / 4);
      *(float4*)&sh.g.Bs[brow][nq * 4] =
          *(const float4*)&W[(size_t)(k0 + brow) * N + n0 + nq * 4];
    }
    __syncthreads();
#pragma unroll
    for (int k = 0; k < BK; ++k) {
      float a[TM], b[TN];
#pragma unroll
      for (int i = 0; i < TM; ++i) a[i] = sh.g.As[k][tr * TM + i];
#pragma unroll
      for (int j = 0; j < TN; ++j) b[j] = sh.g.Bs[k][tc * TN + j];
#pragma unroll
      for (int i = 0; i < TM; ++i)
#pragma unroll
        for (int j = 0; j < TN; ++j) acc[i][j] += a[i] * b[j];
    }
    __syncthreads();
  }
  const float s_alpha = 1.6732632423543772f, s_scale = 1.0507009873554805f;
#pragma unroll
  for (int i = 0; i < TM; ++i) {
    int row = m0 + tr * TM + i;
    float4 outv;
    float tmp4[4];
#pragma unroll
    for (int j = 0; j < TN; ++j) {
      float v = acc[i][j] + bb[j];
      v = s_scale * (v > 0.f ? v : s_alpha * expm1f(v));
      tmp4[j] = v;
    }
    outv.x = tmp4[0]; outv.y = tmp4[1]; outv.z = tmp4[2]; outv.w = tmp4[3];
    *(float4*)&C[(size_t)row * N + n0 + tc * TN] = outv;
  }
}

// ---------------------------------------------------------------------------
// sparse attention: block per (b,i), 512 threads = 8 waves (one per head).
// ---------------------------------------------------------------------------
__global__ __launch_bounds__(512) void attn_kernel(
    const float* __restrict__ q, const float* __restrict__ k,
    const float* __restrict__ v, const float* __restrict__ pos_ind,
    const float* __restrict__ fmask, const float* __restrict__ T,
    const float* __restrict__ pbm, float* __restrict__ o) {
  __shared__ float sT[2048];
  __shared__ float qrow[256];
  __shared__ float psh[8][64];
  __shared__ int jlist[64];
  __shared__ int p0s[64];
  __shared__ int p1s[64];
  __shared__ int wcnt[8];
  __shared__ int woff[8];
  __shared__ int njs;
  int t = threadIdx.x;
  int bi = blockIdx.x;  // b*L + i
  int b = bi >> 9, i = bi & 511;
  for (int e = t; e < 2048; e += 512) sT[e] = T[e];
  if (t < 256) qrow[t] = q[(size_t)bi * D + t];
  float fmi = fmask[bi];
  __syncthreads();
  {
    int j = t;
    float fmj = fmask[b * L + j];
    bool aj = (1.0f - fmj) > 0.0f;
    bool ai = (1.0f - fmi) > 0.0f;
    int di = i - j;
    bool local_np = (di >= 9) || (di <= -8);
    int ad = di < 0 ? -di : di;
    bool dil_np = (ad & 15) != 0;
    bool m = (dil_np || aj || ai) && (local_np || aj);
    unsigned long long ball = __ballot(!m);
    int wv = t >> 6;
    if ((t & 63) == 0) wcnt[wv] = __popcll(ball);
    __syncthreads();
    if (t == 0) {
      int s = 0;
      for (int w = 0; w < 8; ++w) { woff[w] = s; s += wcnt[w]; }
      njs = s;
    }
    __syncthreads();
    if (!m) {
      int slot = woff[wv] +
                 __popcll(ball & ((1ull << (unsigned)(t & 63)) - 1ull));
      jlist[slot] = j;
      int pidx = ((size_t)bi * L + j) * 2;
      int p0 = (int)floorf(pos_ind[pidx]);
      int p1 = (int)floorf(pos_ind[pidx + 1]);
      p0s[slot] = min(max(p0, -64), 63) + 64;
      p1s[slot] = min(max(p1, -64), 63) + 192;
    }
  }
  __syncthreads();
  int nj = njs;
  int h = t >> 6, sl = t & 63;
  if (nj > 0) {
    float sc = -1e30f;
    if (sl < nj) {
      int j = jlist[sl];
      const float4* kr4 = (const float4*)&k[(size_t)(b * L + j) * D + h * 32];
      const float4* qh4 = (const float4*)&qrow[h * 32];
      float dot = 0.f;
#pragma unroll
      for (int dq = 0; dq < 8; ++dq) {
        float4 a = qh4[dq], b2 = kr4[dq];
        dot += a.x * b2.x + a.y * b2.y + a.z * b2.z + a.w * b2.w;
      }
      sc = dot * 0.17677669529663687f + sT[p0s[sl] * 8 + h] +
           sT[p1s[sl] * 8 + h] + pbm[h];
    }
    float mx = sc;
#pragma unroll
    for (int m2 = 32; m2; m2 >>= 1) mx = fmaxf(mx, __shfl_xor(mx, m2));
    float e = (sl < nj) ? expf(sc - mx) : 0.0f;
    float ssum = e;
#pragma unroll
    for (int m2 = 32; m2; m2 >>= 1) ssum += __shfl_xor(ssum, m2);
    psh[h][sl] = e / ssum;
  }
  __syncthreads();
  int d = t & 31, half = (t >> 5) & 1;
  float acc = 0.f;
  if (nj > 0) {
    for (int s2 = half; s2 < nj; s2 += 2) {
      int j = jlist[s2];
      acc += psh[h][s2] * v[(size_t)(b * L + j) * D + h * 32 + d];
    }
  } else {
    for (int j = half; j < L; j += 2)
      acc += v[(size_t)(b * L + j) * D + h * 32 + d];
    acc *= (1.0f / L);
  }
  acc += __shfl_xor(acc, 32);
  if (half == 0) o[(size_t)bi * D + h * 32 + d] = acc;
}

// ---------------------------------------------------------------------------
// x = LayerNorm(resid + y0 + y1) * g + b  — one wave per row, 4 rows/block
// ---------------------------------------------------------------------------
__global__ __launch_bounds__(256) void ln3_kernel(
    const float* __restrict__ resid, const float* __restrict__ y0,
    const float* __restrict__ y1, const float* __restrict__ g,
    const float* __restrict__ bta, float* __restrict__ outx) {
  int t = threadIdx.x;
  int lane = t & 63;
  int row = blockIdx.x * 4 + (t >> 6);
  int base = row * D + lane * 4;
  float4 r = *(const float4*)&resid[base];
  float4 a = *(const float4*)&y0[base];
  float4 c = *(const float4*)&y1[base];
  float val[4] = {r.x + a.x + c.x, r.y + a.y + c.y, r.z + a.z + c.z,
                  r.w + a.w + c.w};
  float s = val[0] + val[1] + val[2] + val[3];
#pragma unroll
  for (int m = 32; m; m >>= 1) s += __shfl_xor(s, m);
  float mean = s * (1.0f / D);
  float vv = 0.f;
#pragma unroll
  for (int e = 0; e < 4; ++e) {
    float dd = val[e] - mean;
    vv += dd * dd;
  }
#pragma unroll
  for (int m = 32; m; m >>= 1) vv += __shfl_xor(vv, m);
  float rs = rsqrtf(vv * (1.0f / D) + 1e-5f);
  float4 gv = *(const float4*)&g[lane * 4];
  float4 bv = *(const float4*)&bta[lane * 4];
  float4 ov;
  ov.x = (val[0] - mean) * rs * gv.x + bv.x;
  ov.y = (val[1] - mean) * rs * gv.y + bv.y;
  ov.z = (val[2] - mean) * rs * gv.z + bv.z;
  ov.w = (val[3] - mean) * rs * gv.w + bv.w;
  *(float4*)&outx[base] = ov;
}

// ---------------------------------------------------------------------------
// final: LN2(resid+y0+y1) + classifier + 2-way softmax — one wave per row
// ---------------------------------------------------------------------------
__global__ __launch_bounds__(256) void ln_cls_kernel(
    const float* __restrict__ resid, const float* __restrict__ y0,
    const float* __restrict__ y1, const float* __restrict__ g,
    const float* __restrict__ bta, const float* __restrict__ cw,
    const float* __restrict__ cb, float* __restrict__ out) {
  int t = threadIdx.x;
  int lane = t & 63;
  int row = blockIdx.x * 4 + (t >> 6);
  int base = row * D + lane * 4;
  float4 r = *(const float4*)&resid[base];
  float4 a = *(const float4*)&y0[base];
  float4 c = *(const float4*)&y1[base];
  float val[4] = {r.x + a.x + c.x, r.y + a.y + c.y, r.z + a.z + c.z,
                  r.w + a.w + c.w};
  float s = val[0] + val[1] + val[2] + val[3];
#pragma unroll
  for (int m = 32; m; m >>= 1) s += __shfl_xor(s, m);
  float mean = s * (1.0f / D);
  float vv = 0.f;
#pragma unroll
  for (int e = 0; e < 4; ++e) {
    float dd = val[e] - mean;
    vv += dd * dd;
  }
#pragma unroll
  for (int m = 32; m; m >>= 1) vv += __shfl_xor(vv, m);
  float rs = rsqrtf(vv * (1.0f / D) + 1e-5f);
  float4 gv = *(const float4*)&g[lane * 4];
  float4 bv = *(const float4*)&bta[lane * 4];
  float xv[4];
  xv[0] = (val[0] - mean) * rs * gv.x + bv.x;
  xv[1] = (val[1] - mean) * rs * gv.y + bv.y;
  xv[2] = (val[2] - mean) * rs * gv.z + bv.z;
  xv[3] = (val[3] - mean) * rs * gv.w + bv.w;
  float l0 = 0.f, l1 = 0.f;
#pragma unroll
  for (int e = 0; e < 4; ++e) {
    int col = lane * 4 + e;
    l0 += xv[e] * cw[col * NCLS + 0];
    l1 += xv[e] * cw[col * NCLS + 1];
  }
#pragma unroll
  for (int m = 32; m; m >>= 1) {
    l0 += __shfl_xor(l0, m);
    l1 += __shfl_xor(l1, m);
  }
  if (lane == 0) {
    l0 += cb[0];
    l1 += cb[1];
    float mx = fmaxf(l0, l1);
    float e0 = expf(l0 - mx), e1 = expf(l1 - mx);
    float inv = 1.0f / (e0 + e1);
    out[row * 2 + 0] = e0 * inv;
    out[row * 2 + 1] = e1 * inv;
  }
}

extern "C" void kernel_launch(void* const* d_in, const int* in_sizes, int n_in,
                              void* d_out, int out_size, void* d_ws,
                              size_t ws_size, hipStream_t stream) {
  const float* feature  = (const float*)d_in[0];
  const float* pos_ind  = (const float*)d_in[1];
  const float* fmaskp   = (const float*)d_in[2];
  const float* w_reduce = (const float*)d_in[3];
  const float* b_reduce = (const float*)d_in[4];
  const float* pos_w    = (const float*)d_in[5];
  const float* pos_b    = (const float*)d_in[6];
  const float* wq       = (const float*)d_in[7];
  const float* wk       = (const float*)d_in[8];
  const float* wv       = (const float*)d_in[9];
  const float* wo       = (const float*)d_in[10];
  const float* ln1_g    = (const float*)d_in[11];
  const float* ln1_b    = (const float*)d_in[12];
  const float* w1       = (const float*)d_in[13];
  const float* b1       = (const float*)d_in[14];
  const float* w2       = (const float*)d_in[15];
  const float* b2       = (const float*)d_in[16];
  const float* ln2_g    = (const float*)d_in[17];
  const float* ln2_b    = (const float*)d_in[18];
  const float* cls_w    = (const float*)d_in[19];
  const float* cls_b    = (const float*)d_in[20];
  float* out = (float*)d_out;

  float* ws = (float*)d_ws;
  float* x     = ws;  ws += B * L * D;
  float* q     = ws;  ws += B * L * D;
  float* kbuf  = ws;  ws += B * L * D;
  float* vbuf  = ws;  ws += B * L * D;
  float* o     = ws;  ws += B * L * D;
  float* tmp   = ws;  ws += B * L * D;
  float* tmp2  = ws;  ws += B * L * D;
  float* ffn_h = ws;  ws += B * L * DFF;
  float* T     = ws;  ws += 2048;
  float* pbm   = ws;  ws += 8;

  const int M = B * L;  // 1024

  // reduce layer GEMM + prep fused (extra grid.x block does prep)
  reduce_prep_kernel<<<dim3(M / 32 + 1, D / 64), 256, 0, stream>>>(
      feature, w_reduce, b_reduce, x, pos_w, pos_b, T, pbm);

  for (int l = 0; l < NL; ++l) {
    // fused QKV (z selects matrix)
    gemm_kernel<32, 64, 16, 2, 4, 0, 1>
        <<<dim3(M / 32, D / 64, 3), 256, 0, stream>>>(
            x, wq + l * D * D, wk + l * D * D, wv + l * D * D, nullptr,
            q, kbuf, vbuf, M, D, D);

    attn_kernel<<<M, 512, 0, stream>>>(q, kbuf, vbuf, pos_ind, fmaskp, T, pbm,
                                       o);

    // wo projection, split-K
    gemm_kernel<32, 64, 16, 2, 4, 0, 2>
        <<<dim3(M / 32, D / 64, 2), 256, 0, stream>>>(
            o, wo + l * D * D, nullptr, nullptr, nullptr, tmp, tmp2, nullptr,
            M, D, D);
    ln3_kernel<<<M / 4, 256, 0, stream>>>(x, tmp, tmp2, ln1_g + l * D,
                                          ln1_b + l * D, x);

    // FFN up (relu), fat 64x64 tile
    gemm_kernel<64, 64, 16, 4, 4, 1, 0>
        <<<dim3(M / 64, DFF / 64), 256, 0, stream>>>(
            x, w1 + l * D * DFF, nullptr, nullptr, b1 + l * DFF, ffn_h,
            nullptr, nullptr, M, DFF, D);
    // FFN down, split-K
    gemm_kernel<32, 64, 16, 2, 4, 0, 2>
        <<<dim3(M / 32, D / 64, 2), 256, 0, stream>>>(
            ffn_h, w2 + l * DFF * D, nullptr, nullptr, b2 + l * D, tmp, tmp2,
            nullptr, M, D, DFF);

    if (l == NL - 1) {
      ln_cls_kernel<<<M / 4, 256, 0, stream>>>(x, tmp, tmp2, ln2_g + l * D,
                                               ln2_b + l * D, cls_w, cls_b,
                                               out);
    } else {
      ln3_kernel<<<M / 4, 256, 0, stream>>>(x, tmp, tmp2, ln2_g + l * D,
                                            ln2_b + l * D, x);
    }
  }
}

// Round 5
// 154.005 us; speedup vs baseline: 3.7997x; 1.5353x over previous
//
#include <hip/hip_runtime.h>
#include <math.h>

#define B 2
#define L 512
#define DIN 400
#define D 256
#define H 8
#define DKK 32
#define DFF 1024
#define NL 2
#define NCLS 2

// ---------------------------------------------------------------------------
// prep: T[t*8+h] = sum_r sin(p*inv[r])*pwm[c*128+r][h] + cos(p*inv[r])*pwm[c*128+64+r][h]
// where t = c*128 + (p+64), pwm[k][h] = mean_d pos_w[k, h*32+d].
// grid 256 blocks (one per t), 512 threads = 8 waves (one per h), lane = r.
// ---------------------------------------------------------------------------
__global__ __launch_bounds__(512) void prep_kernel(
    const float* __restrict__ pos_w, const float* __restrict__ pos_b,
    float* __restrict__ T, float* __restrict__ pbm) {
  int t = blockIdx.x;
  int c = t >> 7;
  float p = (float)((t & 127) - 64);
  int h = threadIdx.x >> 6;
  int r = threadIdx.x & 63;
  float inv = powf(10000.0f, -(float)r * (1.0f / 64.0f));
  float a = p * inv;
  const float* ps = pos_w + (size_t)(c * 128 + r) * D + h * DKK;
  const float* pc = pos_w + (size_t)(c * 128 + 64 + r) * D + h * DKK;
  float ss = 0.f, cs = 0.f;
#pragma unroll
  for (int d = 0; d < DKK; d += 4) {
    float4 v1 = *(const float4*)&ps[d];
    float4 v2 = *(const float4*)&pc[d];
    ss += v1.x + v1.y + v1.z + v1.w;
    cs += v2.x + v2.y + v2.z + v2.w;
  }
  float val = (sinf(a) * ss + cosf(a) * cs) * (1.0f / DKK);
#pragma unroll
  for (int m = 32; m; m >>= 1) val += __shfl_xor(val, m);
  if (r == 0) T[t * 8 + h] = val;
  if (t == 0) {
    float pv = (r < DKK) ? pos_b[h * DKK + r] : 0.0f;
#pragma unroll
    for (int m = 32; m; m >>= 1) pv += __shfl_xor(pv, m);
    if (r == 0) pbm[h] = pv * (1.0f / DKK);
  }
}

// ---------------------------------------------------------------------------
// double-buffered register-tiled GEMM: C = act(A[M,K] @ W[K,N] + bias)
// BM=32, BN=64, BK=16, TM=2, TN=4; 256 threads.
// MODE 0: single. MODE 1: z selects (Wa->Ca)/(Wb->Cb)/(Wc->Cc).
// MODE 2: split-K 2 at kMid: z0 [0,kMid) + bias -> Ca; z1 [kMid,K) -> Cb.
// MODE 3: split-K 4 (K%64==0): z0 + bias -> Ca; z1..3 -> Cb/Cc/Cd.
// ACT: 0 none, 1 relu  (applied only when MODE==0)
// ---------------------------------------------------------------------------
template <int ACT, int MODE>
__global__ __launch_bounds__(256) void gemm_kernel(
    const float* __restrict__ A, const float* __restrict__ Wa,
    const float* __restrict__ Wb, const float* __restrict__ Wc,
    const float* __restrict__ bias, float* __restrict__ Ca,
    float* __restrict__ Cb, float* __restrict__ Cc, float* __restrict__ Cd,
    int M, int N, int K, int kMid) {
  __shared__ float As[2][32][20];
  __shared__ float Bs[2][16][68];
  int tid = threadIdx.x;
  int m0 = blockIdx.x * 32;
  int n0 = blockIdx.y * 64;
  const float* W = Wa;
  float* C = Ca;
  int kBeg = 0, kEnd = K;
  bool useBias = (bias != nullptr);
  if (MODE == 1) {
    W = blockIdx.z == 0 ? Wa : (blockIdx.z == 1 ? Wb : Wc);
    C = blockIdx.z == 0 ? Ca : (blockIdx.z == 1 ? Cb : Cc);
  } else if (MODE == 2) {
    kBeg = blockIdx.z == 0 ? 0 : kMid;
    kEnd = blockIdx.z == 0 ? kMid : K;
    C = blockIdx.z == 0 ? Ca : Cb;
    if (blockIdx.z != 0) useBias = false;
  } else if (MODE == 3) {
    int q = K / 4;
    kBeg = blockIdx.z * q;
    kEnd = kBeg + q;
    C = blockIdx.z == 0 ? Ca
        : (blockIdx.z == 1 ? Cb : (blockIdx.z == 2 ? Cc : Cd));
    if (blockIdx.z != 0) useBias = false;
  }
  // staging maps
  int a_m = tid >> 3;            // 0..31
  int a_k = (tid & 7) * 2;       // 0..14 (float2)
  int b_k = tid >> 4;            // 0..15
  int b_n = (tid & 15) * 4;      // float4
  const float* Aptr = A + (size_t)(m0 + a_m) * K + kBeg + a_k;
  const float* Wptr = W + (size_t)(kBeg + b_k) * N + n0 + b_n;
  int nT = (kEnd - kBeg) / 16;
  int tc = tid & 15;
  int tr = tid >> 4;
  float acc[2][4];
#pragma unroll
  for (int i = 0; i < 2; ++i)
#pragma unroll
    for (int j = 0; j < 4; ++j) acc[i][j] = 0.0f;

  float2 areg = *(const float2*)Aptr;
  float4 breg = *(const float4*)Wptr;
  int buf = 0;
  *(float2*)&As[0][a_m][a_k] = areg;
  *(float4*)&Bs[0][b_k][b_n] = breg;

  for (int t = 0; t < nT; ++t) {
    __syncthreads();  // As/Bs[buf] visible; prior reads of buf^1 complete
    if (t + 1 < nT) {
      areg = *(const float2*)(Aptr + (t + 1) * 16);
      breg = *(const float4*)(Wptr + (size_t)(t + 1) * 16 * N);
    }
#pragma unroll
    for (int k = 0; k < 16; ++k) {
      float a0 = As[buf][tr * 2 + 0][k];
      float a1 = As[buf][tr * 2 + 1][k];
      float4 b = *(const float4*)&Bs[buf][k][tc * 4];
      acc[0][0] += a0 * b.x; acc[0][1] += a0 * b.y;
      acc[0][2] += a0 * b.z; acc[0][3] += a0 * b.w;
      acc[1][0] += a1 * b.x; acc[1][1] += a1 * b.y;
      acc[1][2] += a1 * b.z; acc[1][3] += a1 * b.w;
    }
    __syncthreads();  // all reads of As/Bs[buf] done
    if (t + 1 < nT) {
      *(float2*)&As[buf ^ 1][a_m][a_k] = areg;
      *(float4*)&Bs[buf ^ 1][b_k][b_n] = breg;
    }
    buf ^= 1;
  }
  float bb[4];
#pragma unroll
  for (int j = 0; j < 4; ++j) bb[j] = useBias ? bias[n0 + tc * 4 + j] : 0.0f;
#pragma unroll
  for (int i = 0; i < 2; ++i) {
    int row = m0 + tr * 2 + i;
    float4 outv;
    float v0 = acc[i][0] + bb[0], v1 = acc[i][1] + bb[1];
    float v2 = acc[i][2] + bb[2], v3 = acc[i][3] + bb[3];
    if (MODE == 0 && ACT == 1) {
      v0 = fmaxf(v0, 0.f); v1 = fmaxf(v1, 0.f);
      v2 = fmaxf(v2, 0.f); v3 = fmaxf(v3, 0.f);
    }
    outv.x = v0; outv.y = v1; outv.z = v2; outv.w = v3;
    *(float4*)&C[(size_t)row * N + n0 + tc * 4] = outv;
  }
}

// ---------------------------------------------------------------------------
// x = selu(a + b) elementwise (reduce-layer partial sum), float4
// ---------------------------------------------------------------------------
__global__ __launch_bounds__(256) void selu_add_kernel(
    const float* __restrict__ a, const float* __restrict__ b,
    float* __restrict__ x) {
  int e = (blockIdx.x * 256 + threadIdx.x) * 4;
  float4 va = *(const float4*)&a[e];
  float4 vb = *(const float4*)&b[e];
  const float s_alpha = 1.6732632423543772f, s_scale = 1.0507009873554805f;
  float4 o;
  float v;
  v = va.x + vb.x; o.x = s_scale * (v > 0.f ? v : s_alpha * expm1f(v));
  v = va.y + vb.y; o.y = s_scale * (v > 0.f ? v : s_alpha * expm1f(v));
  v = va.z + vb.z; o.z = s_scale * (v > 0.f ? v : s_alpha * expm1f(v));
  v = va.w + vb.w; o.w = s_scale * (v > 0.f ? v : s_alpha * expm1f(v));
  *(float4*)&x[e] = o;
}

// ---------------------------------------------------------------------------
// sparse attention: block per (b,i), 512 threads = 8 waves (one per head).
// ---------------------------------------------------------------------------
__global__ __launch_bounds__(512) void attn_kernel(
    const float* __restrict__ q, const float* __restrict__ k,
    const float* __restrict__ v, const float* __restrict__ pos_ind,
    const float* __restrict__ fmask, const float* __restrict__ T,
    const float* __restrict__ pbm, float* __restrict__ o) {
  __shared__ float sT[2048];
  __shared__ float qrow[256];
  __shared__ float psh[8][64];
  __shared__ int jlist[64];
  __shared__ int p0s[64];
  __shared__ int p1s[64];
  __shared__ int wcnt[8];
  __shared__ int woff[8];
  __shared__ int njs;
  int t = threadIdx.x;
  int bi = blockIdx.x;  // b*L + i
  int b = bi >> 9, i = bi & 511;
  for (int e = t; e < 2048; e += 512) sT[e] = T[e];
  if (t < 256) qrow[t] = q[(size_t)bi * D + t];
  float fmi = fmask[bi];
  __syncthreads();
  {
    int j = t;
    float fmj = fmask[b * L + j];
    bool aj = (1.0f - fmj) > 0.0f;
    bool ai = (1.0f - fmi) > 0.0f;
    int di = i - j;
    bool local_np = (di >= 9) || (di <= -8);
    int ad = di < 0 ? -di : di;
    bool dil_np = (ad & 15) != 0;
    bool m = (dil_np || aj || ai) && (local_np || aj);
    unsigned long long ball = __ballot(!m);
    int wv = t >> 6;
    if ((t & 63) == 0) wcnt[wv] = __popcll(ball);
    __syncthreads();
    if (t == 0) {
      int s = 0;
      for (int w = 0; w < 8; ++w) { woff[w] = s; s += wcnt[w]; }
      njs = s;
    }
    __syncthreads();
    if (!m) {
      int slot = woff[wv] +
                 __popcll(ball & ((1ull << (unsigned)(t & 63)) - 1ull));
      jlist[slot] = j;
      int pidx = ((size_t)bi * L + j) * 2;
      int p0 = (int)floorf(pos_ind[pidx]);
      int p1 = (int)floorf(pos_ind[pidx + 1]);
      p0s[slot] = min(max(p0, -64), 63) + 64;
      p1s[slot] = min(max(p1, -64), 63) + 192;
    }
  }
  __syncthreads();
  int nj = njs;
  int h = t >> 6, sl = t & 63;
  if (nj > 0) {
    float sc = -1e30f;
    if (sl < nj) {
      int j = jlist[sl];
      const float4* kr4 = (const float4*)&k[(size_t)(b * L + j) * D + h * 32];
      const float4* qh4 = (const float4*)&qrow[h * 32];
      float dot = 0.f;
#pragma unroll
      for (int dq = 0; dq < 8; ++dq) {
        float4 a = qh4[dq], b2 = kr4[dq];
        dot += a.x * b2.x + a.y * b2.y + a.z * b2.z + a.w * b2.w;
      }
      sc = dot * 0.17677669529663687f + sT[p0s[sl] * 8 + h] +
           sT[p1s[sl] * 8 + h] + pbm[h];
    }
    float mx = sc;
#pragma unroll
    for (int m2 = 32; m2; m2 >>= 1) mx = fmaxf(mx, __shfl_xor(mx, m2));
    float e = (sl < nj) ? expf(sc - mx) : 0.0f;
    float ssum = e;
#pragma unroll
    for (int m2 = 32; m2; m2 >>= 1) ssum += __shfl_xor(ssum, m2);
    psh[h][sl] = e / ssum;
  }
  __syncthreads();
  int d = t & 31, half = (t >> 5) & 1;
  float acc = 0.f;
  if (nj > 0) {
    for (int s2 = half; s2 < nj; s2 += 2) {
      int j = jlist[s2];
      acc += psh[h][s2] * v[(size_t)(b * L + j) * D + h * 32 + d];
    }
  } else {
    for (int j = half; j < L; j += 2)
      acc += v[(size_t)(b * L + j) * D + h * 32 + d];
    acc *= (1.0f / L);
  }
  acc += __shfl_xor(acc, 32);
  if (half == 0) o[(size_t)bi * D + h * 32 + d] = acc;
}

// ---------------------------------------------------------------------------
// x = LayerNorm(resid + sum(y[0..NY-1])) * g + b — one wave per row
// ---------------------------------------------------------------------------
template <int NY>
__global__ __launch_bounds__(256) void ln_kernel(
    const float* __restrict__ resid, const float* __restrict__ y0,
    const float* __restrict__ y1, const float* __restrict__ y2,
    const float* __restrict__ y3, const float* __restrict__ g,
    const float* __restrict__ bta, float* __restrict__ outx) {
  const float* ys[4] = {y0, y1, y2, y3};
  int t = threadIdx.x;
  int lane = t & 63;
  int row = blockIdx.x * 4 + (t >> 6);
  int base = row * D + lane * 4;
  float4 r = *(const float4*)&resid[base];
  float val[4] = {r.x, r.y, r.z, r.w};
#pragma unroll
  for (int n = 0; n < NY; ++n) {
    float4 yv = *(const float4*)&ys[n][base];
    val[0] += yv.x; val[1] += yv.y; val[2] += yv.z; val[3] += yv.w;
  }
  float s = val[0] + val[1] + val[2] + val[3];
#pragma unroll
  for (int m = 32; m; m >>= 1) s += __shfl_xor(s, m);
  float mean = s * (1.0f / D);
  float vv = 0.f;
#pragma unroll
  for (int e = 0; e < 4; ++e) {
    float dd = val[e] - mean;
    vv += dd * dd;
  }
#pragma unroll
  for (int m = 32; m; m >>= 1) vv += __shfl_xor(vv, m);
  float rs = rsqrtf(vv * (1.0f / D) + 1e-5f);
  float4 gv = *(const float4*)&g[lane * 4];
  float4 bv = *(const float4*)&bta[lane * 4];
  float4 ov;
  ov.x = (val[0] - mean) * rs * gv.x + bv.x;
  ov.y = (val[1] - mean) * rs * gv.y + bv.y;
  ov.z = (val[2] - mean) * rs * gv.z + bv.z;
  ov.w = (val[3] - mean) * rs * gv.w + bv.w;
  *(float4*)&outx[base] = ov;
}

// ---------------------------------------------------------------------------
// final: LN2(resid + sum y[0..3]) + classifier + 2-way softmax — wave per row
// ---------------------------------------------------------------------------
__global__ __launch_bounds__(256) void ln_cls_kernel(
    const float* __restrict__ resid, const float* __restrict__ y0,
    const float* __restrict__ y1, const float* __restrict__ y2,
    const float* __restrict__ y3, const float* __restrict__ g,
    const float* __restrict__ bta, const float* __restrict__ cw,
    const float* __restrict__ cb, float* __restrict__ out) {
  int t = threadIdx.x;
  int lane = t & 63;
  int row = blockIdx.x * 4 + (t >> 6);
  int base = row * D + lane * 4;
  float4 r = *(const float4*)&resid[base];
  float4 a = *(const float4*)&y0[base];
  float4 c = *(const float4*)&y1[base];
  float4 d2 = *(const float4*)&y2[base];
  float4 e2 = *(const float4*)&y3[base];
  float val[4] = {r.x + a.x + c.x + d2.x + e2.x,
                  r.y + a.y + c.y + d2.y + e2.y,
                  r.z + a.z + c.z + d2.z + e2.z,
                  r.w + a.w + c.w + d2.w + e2.w};
  float s = val[0] + val[1] + val[2] + val[3];
#pragma unroll
  for (int m = 32; m; m >>= 1) s += __shfl_xor(s, m);
  float mean = s * (1.0f / D);
  float vv = 0.f;
#pragma unroll
  for (int e = 0; e < 4; ++e) {
    float dd = val[e] - mean;
    vv += dd * dd;
  }
#pragma unroll
  for (int m = 32; m; m >>= 1) vv += __shfl_xor(vv, m);
  float rs = rsqrtf(vv * (1.0f / D) + 1e-5f);
  float4 gv = *(const float4*)&g[lane * 4];
  float4 bv = *(const float4*)&bta[lane * 4];
  float xv[4];
  xv[0] = (val[0] - mean) * rs * gv.x + bv.x;
  xv[1] = (val[1] - mean) * rs * gv.y + bv.y;
  xv[2] = (val[2] - mean) * rs * gv.z + bv.z;
  xv[3] = (val[3] - mean) * rs * gv.w + bv.w;
  float l0 = 0.f, l1 = 0.f;
#pragma unroll
  for (int e = 0; e < 4; ++e) {
    int col = lane * 4 + e;
    l0 += xv[e] * cw[col * NCLS + 0];
    l1 += xv[e] * cw[col * NCLS + 1];
  }
#pragma unroll
  for (int m = 32; m; m >>= 1) {
    l0 += __shfl_xor(l0, m);
    l1 += __shfl_xor(l1, m);
  }
  if (lane == 0) {
    l0 += cb[0];
    l1 += cb[1];
    float mx = fmaxf(l0, l1);
    float e0 = expf(l0 - mx), e1 = expf(l1 - mx);
    float inv = 1.0f / (e0 + e1);
    out[row * 2 + 0] = e0 * inv;
    out[row * 2 + 1] = e1 * inv;
  }
}

extern "C" void kernel_launch(void* const* d_in, const int* in_sizes, int n_in,
                              void* d_out, int out_size, void* d_ws,
                              size_t ws_size, hipStream_t stream) {
  const float* feature  = (const float*)d_in[0];
  const float* pos_ind  = (const float*)d_in[1];
  const float* fmaskp   = (const float*)d_in[2];
  const float* w_reduce = (const float*)d_in[3];
  const float* b_reduce = (const float*)d_in[4];
  const float* pos_w    = (const float*)d_in[5];
  const float* pos_b    = (const float*)d_in[6];
  const float* wq       = (const float*)d_in[7];
  const float* wk       = (const float*)d_in[8];
  const float* wv       = (const float*)d_in[9];
  const float* wo       = (const float*)d_in[10];
  const float* ln1_g    = (const float*)d_in[11];
  const float* ln1_b    = (const float*)d_in[12];
  const float* w1       = (const float*)d_in[13];
  const float* b1       = (const float*)d_in[14];
  const float* w2       = (const float*)d_in[15];
  const float* b2       = (const float*)d_in[16];
  const float* ln2_g    = (const float*)d_in[17];
  const float* ln2_b    = (const float*)d_in[18];
  const float* cls_w    = (const float*)d_in[19];
  const float* cls_b    = (const float*)d_in[20];
  float* out = (float*)d_out;

  float* ws = (float*)d_ws;
  float* x     = ws;  ws += B * L * D;
  float* q     = ws;  ws += B * L * D;
  float* kbuf  = ws;  ws += B * L * D;
  float* vbuf  = ws;  ws += B * L * D;
  float* o     = ws;  ws += B * L * D;
  float* tmp   = ws;  ws += B * L * D;
  float* tmp2  = ws;  ws += B * L * D;
  float* tmp3  = ws;  ws += B * L * D;
  float* tmp4  = ws;  ws += B * L * D;
  float* ffn_h = ws;  ws += B * L * DFF;
  float* T     = ws;  ws += 2048;
  float* pbm   = ws;  ws += 8;

  const int M = B * L;  // 1024

  prep_kernel<<<256, 512, 0, stream>>>(pos_w, pos_b, T, pbm);

  // reduce layer: split-K 2 at 208, then x = selu(tmp + tmp2)
  gemm_kernel<0, 2><<<dim3(M / 32, D / 64, 2), 256, 0, stream>>>(
      feature, w_reduce, nullptr, nullptr, b_reduce, tmp, tmp2, nullptr,
      nullptr, M, D, DIN, 208);
  selu_add_kernel<<<M * D / 1024, 256, 0, stream>>>(tmp, tmp2, x);

  for (int l = 0; l < NL; ++l) {
    // fused QKV (z selects matrix)
    gemm_kernel<0, 1><<<dim3(M / 32, D / 64, 3), 256, 0, stream>>>(
        x, wq + l * D * D, wk + l * D * D, wv + l * D * D, nullptr,
        q, kbuf, vbuf, nullptr, M, D, D, 0);

    attn_kernel<<<M, 512, 0, stream>>>(q, kbuf, vbuf, pos_ind, fmaskp, T, pbm,
                                       o);

    // wo projection, split-K 2
    gemm_kernel<0, 2><<<dim3(M / 32, D / 64, 2), 256, 0, stream>>>(
        o, wo + l * D * D, nullptr, nullptr, nullptr, tmp, tmp2, nullptr,
        nullptr, M, D, D, 128);
    ln_kernel<2><<<M / 4, 256, 0, stream>>>(x, tmp, tmp2, nullptr, nullptr,
                                            ln1_g + l * D, ln1_b + l * D, x);

    // FFN up (relu)
    gemm_kernel<1, 0><<<dim3(M / 32, DFF / 64), 256, 0, stream>>>(
        x, w1 + l * D * DFF, nullptr, nullptr, b1 + l * DFF, ffn_h, nullptr,
        nullptr, nullptr, M, DFF, D, 0);
    // FFN down, split-K 4
    gemm_kernel<0, 3><<<dim3(M / 32, D / 64, 4), 256, 0, stream>>>(
        ffn_h, w2 + l * DFF * D, nullptr, nullptr, b2 + l * D, tmp, tmp2,
        tmp3, tmp4, M, D, DFF, 0);

    if (l == NL - 1) {
      ln_cls_kernel<<<M / 4, 256, 0, stream>>>(x, tmp, tmp2, tmp3, tmp4,
                                               ln2_g + l * D, ln2_b + l * D,
                                               cls_w, cls_b, out);
    } else {
      ln_kernel<4><<<M / 4, 256, 0, stream>>>(x, tmp, tmp2, tmp3, tmp4,
                                              ln2_g + l * D, ln2_b + l * D, x);
    }
  }
}